// Round 10
// baseline (583.019 us; speedup 1.0000x reference)
//
#include <hip/hip_runtime.h>
#include <hip/hip_fp16.h>
#include <hip/hip_cooperative_groups.h>

namespace cg = cooperative_groups;

#define N_NODES 50000
#define N_EDGES 800000
#define FDIM 64
#define N_GRAPHS 500
#define OUTF 10
#define SENT N_NODES
#define BLK 256
#define NTILES (N_NODES / 16)            // 3125 gcn tiles (16 nodes each)
#define ATILES ((N_NODES + 255) / 256)   // 196 alloc tiles
#define EDGE_BLOCKS 3125                 // 3125*256 == 800000 exactly

struct __align__(8) H4 { __half2 a, b; };

__device__ __forceinline__ float rl(float v, int l) {
    return __int_as_float(__builtin_amdgcn_readlane(__float_as_int(v), l));
}

struct Args {
    const float* x; const int* src; const int* dst; const int* batch;
    const float* W1; const float* b1; const float* W2; const float* b2;
    const float* Wc; const float* bc; float* out;
    int* deg; int* fill; int* cursor; int2* rowinfo; float* dinv; int* start;
    int* csr_src; __half* hsx; __half* hs1;
};

union ShMem {                            // phases never overlap -> 16 KB total
    float Ws[FDIM * FDIM];
    struct { int wsum[4]; int base; float sdinv[BLK]; } al;
    struct { float ps[4 * 64]; float pm[64]; float logits[OUTF]; } po;
};

// ==================== cooperative mega-kernel ====================
__global__ __launch_bounds__(BLK, 2) void mega(Args a) {
    cg::grid_group grid = cg::this_grid();
    const int tid = threadIdx.x, bid = blockIdx.x, nb = gridDim.x;
    const int gtid = bid * BLK + tid, gsize = nb * BLK;
    const int lane = tid & 63, w = tid >> 6;
    const int L = lane & 15, q = lane >> 4;

    __shared__ ShMem sh;

    // ---- Phase A: zero deg/fill/cursor + fp16 sentinel rows ----
    for (int i = gtid; i < 2 * N_NODES + 1; i += gsize) a.deg[i] = 0;
    if (bid == 0 && tid < 2 * FDIM) {
        __half z = __float2half(0.f);
        if (tid < FDIM) a.hsx[(size_t)N_NODES * FDIM + tid] = z;
        else            a.hs1[(size_t)N_NODES * FDIM + tid - FDIM] = z;
    }
    grid.sync();

    // ---- Phase B: degree histogram + seg starts ----
    for (int e = gtid; e < N_EDGES; e += gsize) atomicAdd(&a.deg[a.dst[e]], 1);
    for (int i = gtid; i <= N_NODES; i += gsize) {
        int b  = (i < N_NODES) ? a.batch[i] : N_GRAPHS;
        int bp = (i == 0) ? -1 : a.batch[i - 1];
        for (int g = bp + 1; g <= b; ++g) a.start[g] = i;
    }
    grid.sync();

    // ---- Phase C: row alloc (block scan + 1 cursor atomic) + prescale ----
    if (bid < ATILES) {
        int i = bid * BLK + tid;
        int d = (i < N_NODES) ? a.deg[i] : 0;
        int v = d;
        #pragma unroll
        for (int off = 1; off < 64; off <<= 1) {
            int t = __shfl_up(v, off);
            if (lane >= off) v += t;
        }
        if (lane == 63) sh.al.wsum[w] = v;
        __syncthreads();
        if (tid == 0) {
            int run = 0;
            #pragma unroll
            for (int k = 0; k < 4; ++k) { int t = sh.al.wsum[k]; sh.al.wsum[k] = run; run += t; }
            sh.al.base = atomicAdd(a.cursor, run);
        }
        __syncthreads();
        float dn = rsqrtf((float)d + 1.0f);     // +1 self-loop
        int myBase = sh.al.base + sh.al.wsum[w] + (v - d);
        if (i < N_NODES) {
            a.rowinfo[i] = make_int2(myBase, d);
            a.dinv[i] = dn;
        }
        sh.al.sdinv[tid] = dn;
        __syncthreads();
        int n0 = bid * BLK;
        #pragma unroll 4
        for (int it = 0; it < 16; ++it) {
            int gid = (n0 << 4) + it * BLK + tid;   // float4 index
            int n = gid >> 4;
            if (n >= N_NODES) break;
            float s = sh.al.sdinv[n - n0];
            float4 vv = ((const float4*)a.x)[gid];
            H4 o;
            o.a = __floats2half2_rn(vv.x * s, vv.y * s);
            o.b = __floats2half2_rn(vv.z * s, vv.w * s);
            ((H4*)a.hsx)[gid] = o;
        }
    }
    grid.sync();

    // ---- Phase D: XCD-affinity CSR fill ----
    {
        int myx = bid & 7, cid = bid >> 3, nch = nb >> 3;
        for (int e = cid * BLK + tid; e < N_EDGES; e += nch * BLK) {
            int d = a.dst[e];
            if (((d >> 5) & 7) != myx) continue;
            int pos = a.rowinfo[d].x + atomicAdd(&a.fill[d], 1);
            a.csr_src[pos] = a.src[e];
        }
    }
    grid.sync();

    // ---- Phases E/F: two fused GCN layers ----
    #pragma unroll 1
    for (int layer = 0; layer < 2; ++layer) {
        const float* Wg = layer == 0 ? a.W1 : a.W2;
        const float* bg = layer == 0 ? a.b1 : a.b2;
        const __half* hin = layer == 0 ? a.hsx : a.hs1;
        __half* hout = layer == 0 ? a.hs1 : a.hsx;   // layer2 out aliases hsx
        bool scaleOut = (layer == 0);

        #pragma unroll
        for (int i = 0; i < 16; ++i) sh.Ws[tid + i * BLK] = Wg[tid + i * BLK];
        __syncthreads();

        for (int t = bid; t < NTILES; t += nb) {
            int nodeBase = (t * 4 + w) * 4;
            int myN = nodeBase + q;
            float dn = a.dinv[myN];
            int2 ri = a.rowinfo[myN];
            int row = ri.x, d = ri.y;
            int dpad = (d + 7) & ~7;
            int last = row + d - 1;              // valid only when d > 0

            H4 sv = *(const H4*)(hin + (size_t)myN * FDIM + 4 * L);
            float2 slo = __half22float2(sv.a), shi = __half22float2(sv.b);
            float4 acc0 = make_float4(slo.x, slo.y, shi.x, shi.y);
            float4 acc1 = make_float4(0.f, 0.f, 0.f, 0.f);

            for (int base = 0; base < dpad; base += 8) {
                #pragma unroll
                for (int j = 0; j < 8; ++j) {
                    int e = base + j;
                    int idx = min(row + e, last);
                    int s = a.csr_src[idx];
                    s = (e < d) ? s : SENT;      // tail -> cached zero row
                    H4 hv = *(const H4*)(hin + (size_t)s * FDIM + 4 * L);
                    float2 lo = __half22float2(hv.a), hi = __half22float2(hv.b);
                    if (j & 1) { acc1.x += lo.x; acc1.y += lo.y; acc1.z += hi.x; acc1.w += hi.y; }
                    else       { acc0.x += lo.x; acc0.y += lo.y; acc0.z += hi.x; acc0.w += hi.y; }
                }
            }
            float4 acc = make_float4((acc0.x + acc1.x) * dn, (acc0.y + acc1.y) * dn,
                                     (acc0.z + acc1.z) * dn, (acc0.w + acc1.w) * dn);

            float b0 = bg[lane];
            float o0 = b0, o1 = b0, o2 = b0, o3 = b0;
            #pragma unroll
            for (int k = 0; k < 64; ++k) {
                float wv = sh.Ws[k * 64 + lane];
                int sl = k >> 2;
                float comp = (k & 3) == 0 ? acc.x : (k & 3) == 1 ? acc.y
                           : (k & 3) == 2 ? acc.z : acc.w;
                o0 = fmaf(rl(comp, sl),      wv, o0);
                o1 = fmaf(rl(comp, sl + 16), wv, o1);
                o2 = fmaf(rl(comp, sl + 32), wv, o2);
                o3 = fmaf(rl(comp, sl + 48), wv, o3);
            }
            o0 = fmaxf(o0, 0.f); o1 = fmaxf(o1, 0.f); o2 = fmaxf(o2, 0.f); o3 = fmaxf(o3, 0.f);
            if (scaleOut) {
                o0 *= rl(dn, 0); o1 *= rl(dn, 16); o2 *= rl(dn, 32); o3 *= rl(dn, 48);
            }
            hout[(size_t)(nodeBase + 0) * FDIM + lane] = __float2half_rn(o0);
            hout[(size_t)(nodeBase + 1) * FDIM + lane] = __float2half_rn(o1);
            hout[(size_t)(nodeBase + 2) * FDIM + lane] = __float2half_rn(o2);
            hout[(size_t)(nodeBase + 3) * FDIM + lane] = __float2half_rn(o3);
        }
        grid.sync();
    }

    // ---- Phase G: mean-pool + head + log_softmax ----
    const __half* hfin = a.hsx;
    for (int g = bid; g < N_GRAPHS; g += nb) {
        int s0 = a.start[g], s1 = a.start[g + 1];
        int sub = w * 4 + q;
        float4 acc = make_float4(0.f, 0.f, 0.f, 0.f);
        for (int i = s0 + sub; i < s1; i += 16) {
            H4 hv = *(const H4*)(hfin + (size_t)i * FDIM + 4 * L);
            float2 lo = __half22float2(hv.a), hi = __half22float2(hv.b);
            acc.x += lo.x; acc.y += lo.y; acc.z += hi.x; acc.w += hi.y;
        }
        #pragma unroll
        for (int m = 16; m <= 32; m <<= 1) {
            acc.x += __shfl_xor(acc.x, m);
            acc.y += __shfl_xor(acc.y, m);
            acc.z += __shfl_xor(acc.z, m);
            acc.w += __shfl_xor(acc.w, m);
        }
        if (q == 0) *(float4*)(sh.po.ps + w * 64 + 4 * L) = acc;
        __syncthreads();
        if (tid < 64) {
            float tot = sh.po.ps[tid] + sh.po.ps[64 + tid] + sh.po.ps[128 + tid] + sh.po.ps[192 + tid];
            float c = (float)((s1 - s0) > 1 ? (s1 - s0) : 1);
            sh.po.pm[tid] = tot / c;
        }
        __syncthreads();
        if (tid < OUTF) {
            float av = a.bc[tid];
            #pragma unroll
            for (int k = 0; k < 64; ++k) av = fmaf(sh.po.pm[k], a.Wc[k * OUTF + tid], av);
            sh.po.logits[tid] = av;
        }
        __syncthreads();
        if (tid == 0) {
            float m = -1e30f;
            #pragma unroll
            for (int i = 0; i < OUTF; ++i) m = fmaxf(m, sh.po.logits[i]);
            float s = 0.f;
            #pragma unroll
            for (int i = 0; i < OUTF; ++i) s += __expf(sh.po.logits[i] - m);
            float lse = m + __logf(s);
            #pragma unroll
            for (int i = 0; i < OUTF; ++i) a.out[g * OUTF + i] = sh.po.logits[i] - lse;
        }
        __syncthreads();
    }
}

// ==================== fallback path (round-8 proven kernels) ====================
__global__ void count_deg_seg(const int* __restrict__ dst, int* __restrict__ deg,
                              const int* __restrict__ batch, int* __restrict__ start,
                              __half* __restrict__ s0, __half* __restrict__ s1) {
    if (blockIdx.x == 0 && threadIdx.x < 2 * FDIM) {
        __half z = __float2half(0.f);
        if (threadIdx.x < FDIM) s0[threadIdx.x] = z;
        else                    s1[threadIdx.x - FDIM] = z;
    }
    if (blockIdx.x < EDGE_BLOCKS) {
        int e = blockIdx.x * 256 + threadIdx.x;
        atomicAdd(&deg[dst[e]], 1);
    } else {
        int i = (blockIdx.x - EDGE_BLOCKS) * 256 + threadIdx.x;
        if (i > N_NODES) return;
        int b  = (i < N_NODES) ? batch[i] : N_GRAPHS;
        int bp = (i == 0) ? -1 : batch[i - 1];
        for (int g = bp + 1; g <= b; ++g) start[g] = i;
    }
}

__global__ __launch_bounds__(256) void alloc_prescale(
    const int* __restrict__ deg, int2* __restrict__ rowinfo,
    float* __restrict__ dinv, int* __restrict__ cursor,
    const float* __restrict__ x, __half* __restrict__ hs) {
    int i = blockIdx.x * 256 + threadIdx.x;
    int d = (i < N_NODES) ? deg[i] : 0;
    int lane = threadIdx.x & 63, w = threadIdx.x >> 6;
    int v = d;
    #pragma unroll
    for (int off = 1; off < 64; off <<= 1) {
        int t = __shfl_up(v, off);
        if (lane >= off) v += t;
    }
    __shared__ int wsum[4];
    __shared__ int base;
    __shared__ float sdinv[256];
    if (lane == 63) wsum[w] = v;
    __syncthreads();
    if (threadIdx.x == 0) {
        int run = 0;
        #pragma unroll
        for (int k = 0; k < 4; ++k) { int t = wsum[k]; wsum[k] = run; run += t; }
        base = atomicAdd(cursor, run);
    }
    __syncthreads();
    float dn = rsqrtf((float)d + 1.0f);
    if (i < N_NODES) {
        rowinfo[i] = make_int2(base + wsum[w] + (v - d), d);
        dinv[i] = dn;
    }
    sdinv[threadIdx.x] = dn;
    __syncthreads();
    int n0 = blockIdx.x * 256;
    #pragma unroll 4
    for (int it = 0; it < 16; ++it) {
        int gid = (n0 << 4) + it * 256 + threadIdx.x;
        int n = gid >> 4;
        if (n >= N_NODES) break;
        float s = sdinv[n - n0];
        float4 vv = ((const float4*)x)[gid];
        H4 o;
        o.a = __floats2half2_rn(vv.x * s, vv.y * s);
        o.b = __floats2half2_rn(vv.z * s, vv.w * s);
        ((H4*)hs)[gid] = o;
    }
}

__global__ __launch_bounds__(256) void fill_csr_xcd(
    const int* __restrict__ src, const int* __restrict__ dst,
    const int2* __restrict__ rowinfo, int* __restrict__ fill,
    int* __restrict__ csr_src) {
    int myx = blockIdx.x & 7;
    int cid = blockIdx.x >> 3;
    int nch = gridDim.x >> 3;
    for (int e = cid * 256 + threadIdx.x; e < N_EDGES; e += nch * 256) {
        int d = dst[e];
        if (((d >> 5) & 7) != myx) continue;
        int pos = rowinfo[d].x + atomicAdd(&fill[d], 1);
        csr_src[pos] = src[e];
    }
}

template <bool SCALE_OUT>
__global__ __launch_bounds__(256) void gcn_fused(
    const int2* __restrict__ rowinfo, const int* __restrict__ csr_src,
    const float* __restrict__ dinv, const __half* __restrict__ hs,
    const float* __restrict__ W, const float* __restrict__ bias,
    __half* __restrict__ out) {
    __shared__ float Ws[FDIM * FDIM];
    int tid = threadIdx.x;
    int lane = tid & 63;
    int L = lane & 15, q = lane >> 4;
    int nodeBase = (blockIdx.x * 4 + (tid >> 6)) * 4;
    int myN = nodeBase + q;

    float dn = dinv[myN];
    int2 ri = rowinfo[myN];
    int row = ri.x, d = ri.y;
    int dpad = (d + 7) & ~7;
    int last = row + d - 1;

    H4 sv = *(const H4*)(hs + (size_t)myN * FDIM + 4 * L);
    float2 slo = __half22float2(sv.a), shi = __half22float2(sv.b);
    float4 acc0 = make_float4(slo.x, slo.y, shi.x, shi.y);
    float4 acc1 = make_float4(0.f, 0.f, 0.f, 0.f);

    #pragma unroll
    for (int i = 0; i < 16; ++i) Ws[tid + i * 256] = W[tid + i * 256];
    __syncthreads();

    for (int base = 0; base < dpad; base += 8) {
        #pragma unroll
        for (int j = 0; j < 8; ++j) {
            int e = base + j;
            int idx = min(row + e, last);
            int s = csr_src[idx];
            s = (e < d) ? s : SENT;
            H4 hv = *(const H4*)(hs + (size_t)s * FDIM + 4 * L);
            float2 lo = __half22float2(hv.a), hi = __half22float2(hv.b);
            if (j & 1) { acc1.x += lo.x; acc1.y += lo.y; acc1.z += hi.x; acc1.w += hi.y; }
            else       { acc0.x += lo.x; acc0.y += lo.y; acc0.z += hi.x; acc0.w += hi.y; }
        }
    }
    float4 acc = make_float4((acc0.x + acc1.x) * dn, (acc0.y + acc1.y) * dn,
                             (acc0.z + acc1.z) * dn, (acc0.w + acc1.w) * dn);

    float b0 = bias[lane];
    float o0 = b0, o1 = b0, o2 = b0, o3 = b0;
    #pragma unroll
    for (int k = 0; k < 64; ++k) {
        float wv = Ws[k * 64 + lane];
        int sl = k >> 2;
        float comp = (k & 3) == 0 ? acc.x : (k & 3) == 1 ? acc.y : (k & 3) == 2 ? acc.z : acc.w;
        o0 = fmaf(rl(comp, sl),      wv, o0);
        o1 = fmaf(rl(comp, sl + 16), wv, o1);
        o2 = fmaf(rl(comp, sl + 32), wv, o2);
        o3 = fmaf(rl(comp, sl + 48), wv, o3);
    }
    o0 = fmaxf(o0, 0.f); o1 = fmaxf(o1, 0.f); o2 = fmaxf(o2, 0.f); o3 = fmaxf(o3, 0.f);
    if (SCALE_OUT) {
        o0 *= rl(dn, 0); o1 *= rl(dn, 16); o2 *= rl(dn, 32); o3 *= rl(dn, 48);
    }
    out[(size_t)(nodeBase + 0) * FDIM + lane] = __float2half_rn(o0);
    out[(size_t)(nodeBase + 1) * FDIM + lane] = __float2half_rn(o1);
    out[(size_t)(nodeBase + 2) * FDIM + lane] = __float2half_rn(o2);
    out[(size_t)(nodeBase + 3) * FDIM + lane] = __float2half_rn(o3);
}

__global__ __launch_bounds__(256) void pool_head(
    const __half* __restrict__ h, const int* __restrict__ start,
    const float* __restrict__ Wc, const float* __restrict__ bc,
    float* __restrict__ out) {
    int g = blockIdx.x;
    int tid = threadIdx.x;
    int lane = tid & 63, w = tid >> 6;
    int L = lane & 15, q = lane >> 4;
    int s0 = start[g], s1 = start[g + 1];
    int sub = w * 4 + q;

    float4 acc = make_float4(0.f, 0.f, 0.f, 0.f);
    for (int i = s0 + sub; i < s1; i += 16) {
        H4 hv = *(const H4*)(h + (size_t)i * FDIM + 4 * L);
        float2 lo = __half22float2(hv.a), hi = __half22float2(hv.b);
        acc.x += lo.x; acc.y += lo.y; acc.z += hi.x; acc.w += hi.y;
    }
    #pragma unroll
    for (int m = 16; m <= 32; m <<= 1) {
        acc.x += __shfl_xor(acc.x, m);
        acc.y += __shfl_xor(acc.y, m);
        acc.z += __shfl_xor(acc.z, m);
        acc.w += __shfl_xor(acc.w, m);
    }
    __shared__ float ps[4 * 64];
    __shared__ float pm[64];
    __shared__ float logits[OUTF];
    if (q == 0) *(float4*)(ps + w * 64 + 4 * L) = acc;
    __syncthreads();
    if (tid < 64) {
        float tot = ps[tid] + ps[64 + tid] + ps[128 + tid] + ps[192 + tid];
        float c = (float)((s1 - s0) > 1 ? (s1 - s0) : 1);
        pm[tid] = tot / c;
    }
    __syncthreads();
    if (tid < OUTF) {
        float a = bc[tid];
        #pragma unroll
        for (int k = 0; k < 64; ++k) a = fmaf(pm[k], Wc[k * OUTF + tid], a);
        logits[tid] = a;
    }
    __syncthreads();
    if (tid == 0) {
        float m = -1e30f;
        #pragma unroll
        for (int i = 0; i < OUTF; ++i) m = fmaxf(m, logits[i]);
        float s = 0.f;
        #pragma unroll
        for (int i = 0; i < OUTF; ++i) s += __expf(logits[i] - m);
        float lse = m + __logf(s);
        #pragma unroll
        for (int i = 0; i < OUTF; ++i) out[g * OUTF + i] = logits[i] - lse;
    }
}

extern "C" void kernel_launch(void* const* d_in, const int* in_sizes, int n_in,
                              void* d_out, int out_size, void* d_ws, size_t ws_size,
                              hipStream_t stream) {
    const int* ei = (const int*)d_in[1];

    // workspace layout (int units)
    int*    ws      = (int*)d_ws;
    int*    deg     = ws;                                // 50000 } zeroed
    int*    fill    = deg + N_NODES;                     // 50000 } in phase A /
    int*    cursor  = fill + N_NODES;                    // 1     } memset (fallback)
    int*    pad0    = cursor + 1;                        // 1 (align)
    int2*   rowinfo = (int2*)(pad0 + 1);                 // 50000 int2
    float*  dinv    = (float*)(rowinfo + N_NODES);       // 50000
    int*    start   = (int*)(dinv + N_NODES);            // 504
    int*    csr_src = start + N_GRAPHS + 6;              // N_EDGES + pad
    __half* hsx     = (__half*)(csr_src + N_EDGES + 4);  // (N_NODES+1)*64 halves
    __half* hs1     = hsx + (size_t)(N_NODES + 1) * FDIM;

    Args a;
    a.x  = (const float*)d_in[0];
    a.src = ei;
    a.dst = ei + N_EDGES;
    a.batch = (const int*)d_in[2];
    a.W1 = (const float*)d_in[3];  a.b1 = (const float*)d_in[4];
    a.W2 = (const float*)d_in[5];  a.b2 = (const float*)d_in[6];
    a.Wc = (const float*)d_in[7];  a.bc = (const float*)d_in[8];
    a.out = (float*)d_out;
    a.deg = deg; a.fill = fill; a.cursor = cursor; a.rowinfo = rowinfo;
    a.dinv = dinv; a.start = start; a.csr_src = csr_src;
    a.hsx = hsx; a.hs1 = hs1;

    // ---- try cooperative mega-kernel with runtime-validated grid ----
    hipError_t lerr = hipErrorUnknown;
    int maxB = 0;
    hipError_t qerr = hipOccupancyMaxActiveBlocksPerMultiprocessor(
        &maxB, (const void*)mega, BLK, 0);
    if (qerr == hipSuccess && maxB > 0) {
        int grid = maxB * 256;               // 256 CUs on MI355X
        if (grid > 1024) grid = 1024;
        if (grid >= ATILES + 64) {           // need >=196 blocks for phase C
            void* kargs[] = { &a };
            lerr = hipLaunchCooperativeKernel((const void*)mega, dim3(grid),
                                              dim3(BLK), kargs, 0, stream);
        }
    }
    if (lerr == hipSuccess) return;
    (void)hipGetLastError();                 // clear error, take fallback path

    // ---- fallback: proven multi-kernel pipeline (round 8) ----
    hipMemsetAsync(deg, 0, (2 * N_NODES + 1) * sizeof(int), stream);
    const int segBlocks = (N_NODES + 256) / 256;
    count_deg_seg <<<EDGE_BLOCKS + segBlocks, 256, 0, stream>>>(
        a.dst, deg, a.batch, start,
        hsx + (size_t)N_NODES * FDIM, hs1 + (size_t)N_NODES * FDIM);
    alloc_prescale<<<(N_NODES + 255) / 256, 256, 0, stream>>>(deg, rowinfo, dinv, cursor, a.x, hsx);
    fill_csr_xcd  <<<2048, 256, 0, stream>>>(a.src, a.dst, rowinfo, fill, csr_src);
    const int gcnGrid = N_NODES / 16;
    gcn_fused<true ><<<gcnGrid, 256, 0, stream>>>(rowinfo, csr_src, dinv, hsx, a.W1, a.b1, hs1);
    gcn_fused<false><<<gcnGrid, 256, 0, stream>>>(rowinfo, csr_src, dinv, hs1, a.W2, a.b2, hsx);
    pool_head<<<N_GRAPHS, 256, 0, stream>>>(hsx, start, a.Wc, a.bc, a.out);
}

// Round 11
// 186.060 us; speedup vs baseline: 3.1335x; 3.1335x over previous
//
#include <hip/hip_runtime.h>
#include <hip/hip_fp16.h>

#define N_NODES 50000
#define N_EDGES 800000
#define FDIM 64
#define N_GRAPHS 500
#define OUTF 10
#define SENT N_NODES
#define ROWCAP 64                       // fixed CSR row capacity; Poisson(16) tail, P(deg>64)~1e-18
#define FILLB 2048
#define SEGB ((N_NODES + 256) / 256)    // 196

struct __align__(8) H4 { __half2 a, b; };

__device__ __forceinline__ float rl(float v, int l) {
    return __int_as_float(__builtin_amdgcn_readlane(__float_as_int(v), l));
}

// ---------------- single-pass CSR build (deg doubles as cursor) + seg starts ----------------
// XCD affinity: owner(node)=(n>>5)&7, block proxy = blockIdx&7 (heuristic only;
// every edge is handled by exactly one block regardless of placement).
__global__ __launch_bounds__(256) void fill_seg(
    const int* __restrict__ src, const int* __restrict__ dst,
    int* __restrict__ deg, int* __restrict__ csr,
    const int* __restrict__ batch, int* __restrict__ start) {
    int bid = blockIdx.x;
    if (bid < FILLB) {
        int myx = bid & 7, cid = bid >> 3, nch = FILLB >> 3;
        for (int e = cid * 256 + threadIdx.x; e < N_EDGES; e += nch * 256) {
            int d = dst[e];
            if (((d >> 5) & 7) != myx) continue;
            int pos = atomicAdd(&deg[d], 1);
            if (pos < ROWCAP) csr[d * ROWCAP + pos] = src[e];  // clamp is belt-and-braces
        }
    } else {
        // batch sorted: start[g] = first node with batch >= g
        int i = (bid - FILLB) * 256 + threadIdx.x;
        if (i > N_NODES) return;
        int b  = (i < N_NODES) ? batch[i] : N_GRAPHS;
        int bp = (i == 0) ? -1 : batch[i - 1];
        for (int g = bp + 1; g <= b; ++g) start[g] = i;
    }
}

// ---------------- dinv + prescale x -> fp16, + zero sentinel rows ----------------
__global__ __launch_bounds__(256) void prescale(
    const int* __restrict__ deg, const float* __restrict__ x,
    float* __restrict__ dinv, __half* __restrict__ hsx, __half* __restrict__ hs1) {
    if (blockIdx.x == 0 && threadIdx.x < 2 * FDIM) {
        __half z = __float2half(0.f);
        if (threadIdx.x < FDIM) hsx[(size_t)N_NODES * FDIM + threadIdx.x] = z;
        else                    hs1[(size_t)N_NODES * FDIM + threadIdx.x - FDIM] = z;
    }
    __shared__ float sdinv[256];
    int i = blockIdx.x * 256 + threadIdx.x;
    int d = (i < N_NODES) ? deg[i] : 0;
    float dn = rsqrtf((float)d + 1.0f);      // +1 self-loop (deg counts real edges only)
    if (i < N_NODES) dinv[i] = dn;
    sdinv[threadIdx.x] = dn;
    __syncthreads();
    int n0 = blockIdx.x * 256;
    #pragma unroll 4
    for (int it = 0; it < 16; ++it) {
        int gid = (n0 << 4) + it * 256 + threadIdx.x;   // float4 index
        int n = gid >> 4;
        if (n >= N_NODES) break;
        float s = sdinv[n - n0];
        float4 vv = ((const float4*)x)[gid];
        H4 o;
        o.a = __floats2half2_rn(vv.x * s, vv.y * s);
        o.b = __floats2half2_rn(vv.z * s, vv.w * s);
        ((H4*)hsx)[gid] = o;
    }
}

// ---------------- fused GCN layer (fp16 gather, fp32 math) ----------------
// one wave = 4 nodes; 16-lane group per node; fixed-stride CSR rows at n*ROWCAP.
template <bool SCALE_OUT>
__global__ __launch_bounds__(256) void gcn_fused(
    const int* __restrict__ deg, const int* __restrict__ csr,
    const float* __restrict__ dinv, const __half* __restrict__ hs,
    const float* __restrict__ W, const float* __restrict__ bias,
    __half* __restrict__ out) {
    __shared__ float Ws[FDIM * FDIM];
    int tid = threadIdx.x;
    int lane = tid & 63;
    int L = lane & 15, q = lane >> 4;
    int nodeBase = (blockIdx.x * 4 + (tid >> 6)) * 4;   // grid = 3125 exact
    int myN = nodeBase + q;

    float dn = dinv[myN];
    int d = min(deg[myN], ROWCAP);
    int row = myN << 6;                      // myN * ROWCAP
    int dpad = (d + 7) & ~7;
    int last = row + d - 1;                  // valid only when d > 0 (loop skipped otherwise)

    H4 sv = *(const H4*)(hs + (size_t)myN * FDIM + 4 * L);  // self term
    float2 slo = __half22float2(sv.a), shi = __half22float2(sv.b);
    float4 acc0 = make_float4(slo.x, slo.y, shi.x, shi.y);
    float4 acc1 = make_float4(0.f, 0.f, 0.f, 0.f);

    #pragma unroll
    for (int i = 0; i < 16; ++i) Ws[tid + i * 256] = W[tid + i * 256];
    __syncthreads();

    for (int base = 0; base < dpad; base += 8) {
        #pragma unroll
        for (int j = 0; j < 8; ++j) {
            int e = base + j;
            int idx = min(row + e, last);
            int s = csr[idx];
            s = (e < d) ? s : SENT;          // tail -> cached zero row
            H4 hv = *(const H4*)(hs + (size_t)s * FDIM + 4 * L);
            float2 lo = __half22float2(hv.a), hi = __half22float2(hv.b);
            if (j & 1) { acc1.x += lo.x; acc1.y += lo.y; acc1.z += hi.x; acc1.w += hi.y; }
            else       { acc0.x += lo.x; acc0.y += lo.y; acc0.z += hi.x; acc0.w += hi.y; }
        }
    }
    float4 acc = make_float4((acc0.x + acc1.x) * dn, (acc0.y + acc1.y) * dn,
                             (acc0.z + acc1.z) * dn, (acc0.w + acc1.w) * dn);

    float b0 = bias[lane];
    float o0 = b0, o1 = b0, o2 = b0, o3 = b0;
    #pragma unroll
    for (int k = 0; k < 64; ++k) {
        float wv = Ws[k * 64 + lane];
        int sl = k >> 2;
        float comp = (k & 3) == 0 ? acc.x : (k & 3) == 1 ? acc.y : (k & 3) == 2 ? acc.z : acc.w;
        o0 = fmaf(rl(comp, sl),      wv, o0);
        o1 = fmaf(rl(comp, sl + 16), wv, o1);
        o2 = fmaf(rl(comp, sl + 32), wv, o2);
        o3 = fmaf(rl(comp, sl + 48), wv, o3);
    }
    o0 = fmaxf(o0, 0.f); o1 = fmaxf(o1, 0.f); o2 = fmaxf(o2, 0.f); o3 = fmaxf(o3, 0.f);
    if (SCALE_OUT) {   // pre-scale rows by dinv for the next layer's gather
        o0 *= rl(dn, 0); o1 *= rl(dn, 16); o2 *= rl(dn, 32); o3 *= rl(dn, 48);
    }
    out[(size_t)(nodeBase + 0) * FDIM + lane] = __float2half_rn(o0);
    out[(size_t)(nodeBase + 1) * FDIM + lane] = __float2half_rn(o1);
    out[(size_t)(nodeBase + 2) * FDIM + lane] = __float2half_rn(o2);
    out[(size_t)(nodeBase + 3) * FDIM + lane] = __float2half_rn(o3);
}

// ---------------- fused mean-pool + head + log_softmax (fp16 input) ----------------
__global__ __launch_bounds__(256) void pool_head(
    const __half* __restrict__ h, const int* __restrict__ start,
    const float* __restrict__ Wc, const float* __restrict__ bc,
    float* __restrict__ out) {
    int g = blockIdx.x;
    int tid = threadIdx.x;
    int lane = tid & 63, w = tid >> 6;
    int L = lane & 15, q = lane >> 4;
    int s0 = start[g], s1 = start[g + 1];
    int sub = w * 4 + q;

    float4 acc = make_float4(0.f, 0.f, 0.f, 0.f);
    for (int i = s0 + sub; i < s1; i += 16) {
        H4 hv = *(const H4*)(h + (size_t)i * FDIM + 4 * L);
        float2 lo = __half22float2(hv.a), hi = __half22float2(hv.b);
        acc.x += lo.x; acc.y += lo.y; acc.z += hi.x; acc.w += hi.y;
    }
    #pragma unroll
    for (int m = 16; m <= 32; m <<= 1) {
        acc.x += __shfl_xor(acc.x, m);
        acc.y += __shfl_xor(acc.y, m);
        acc.z += __shfl_xor(acc.z, m);
        acc.w += __shfl_xor(acc.w, m);
    }
    __shared__ float ps[4 * 64];
    __shared__ float pm[64];
    __shared__ float logits[OUTF];
    if (q == 0) *(float4*)(ps + w * 64 + 4 * L) = acc;
    __syncthreads();
    if (tid < 64) {
        float tot = ps[tid] + ps[64 + tid] + ps[128 + tid] + ps[192 + tid];
        float c = (float)((s1 - s0) > 1 ? (s1 - s0) : 1);
        pm[tid] = tot / c;
    }
    __syncthreads();
    if (tid < OUTF) {
        float a = bc[tid];
        #pragma unroll
        for (int k = 0; k < 64; ++k) a = fmaf(pm[k], Wc[k * OUTF + tid], a);
        logits[tid] = a;
    }
    __syncthreads();
    if (tid == 0) {
        float m = -1e30f;
        #pragma unroll
        for (int i = 0; i < OUTF; ++i) m = fmaxf(m, logits[i]);
        float s = 0.f;
        #pragma unroll
        for (int i = 0; i < OUTF; ++i) s += __expf(logits[i] - m);
        float lse = m + __logf(s);
        #pragma unroll
        for (int i = 0; i < OUTF; ++i) out[g * OUTF + i] = logits[i] - lse;
    }
}

extern "C" void kernel_launch(void* const* d_in, const int* in_sizes, int n_in,
                              void* d_out, int out_size, void* d_ws, size_t ws_size,
                              hipStream_t stream) {
    const float* x     = (const float*)d_in[0];
    const int*   ei    = (const int*)d_in[1];
    const int*   batch = (const int*)d_in[2];
    const float* W1    = (const float*)d_in[3];
    const float* b1    = (const float*)d_in[4];
    const float* W2    = (const float*)d_in[5];
    const float* b2    = (const float*)d_in[6];
    const float* Wc    = (const float*)d_in[7];
    const float* bc    = (const float*)d_in[8];
    float* out = (float*)d_out;

    const int* src = ei;
    const int* dst = ei + N_EDGES;

    // workspace layout (int units)
    int*    ws    = (int*)d_ws;
    int*    deg   = ws;                                  // 50000 (memset to 0)
    float*  dinv  = (float*)(deg + N_NODES);             // 50000
    int*    start = (int*)(dinv + N_NODES);              // 504
    int*    csr   = start + N_GRAPHS + 8;                // 50000*64 = 3.2M ints
    __half* hsx   = (__half*)(csr + N_NODES * ROWCAP);   // (N_NODES+1)*64 halves
    __half* hs1   = hsx + (size_t)(N_NODES + 1) * FDIM;

    hipMemsetAsync(deg, 0, N_NODES * sizeof(int), stream);

    fill_seg <<<FILLB + SEGB, 256, 0, stream>>>(src, dst, deg, csr, batch, start);
    prescale <<<(N_NODES + 255) / 256, 256, 0, stream>>>(deg, x, dinv, hsx, hs1);

    const int gcnGrid = N_NODES / 16;  // 3125 exact
    gcn_fused<true ><<<gcnGrid, 256, 0, stream>>>(deg, csr, dinv, hsx, W1, b1, hs1);
    gcn_fused<false><<<gcnGrid, 256, 0, stream>>>(deg, csr, dinv, hs1, W2, b2, hsx);

    pool_head<<<N_GRAPHS, 256, 0, stream>>>(hsx, start, Wc, bc, out);
}